// Round 4
// baseline (87.581 us; speedup 1.0000x reference)
//
#include <hip/hip_runtime.h>
#include <hip/hip_bf16.h>

#define BB  4
#define CC  128
#define ICH 64
#define NN  4096
#define SS  8            // KV split factor
#define KSPLIT (NN / SS) // 512 keys per block
#define MT (KSPLIT / 64) // 8 key-tiles per block

typedef __attribute__((ext_vector_type(4)))  float f32x4;
typedef __attribute__((ext_vector_type(16))) float f32x16;
typedef __attribute__((ext_vector_type(8)))  short bf16x8;
typedef __attribute__((ext_vector_type(4)))  unsigned u32x4;
typedef unsigned short u16;

static __device__ __forceinline__ f32x16 mfma32(bf16x8 a, bf16x8 b, f32x16 c) {
  return __builtin_amdgcn_mfma_f32_32x32x16_bf16(a, b, c, 0, 0, 0);
}
static __device__ __forceinline__ u16 f2bf(float f) {
  __hip_bfloat16 h = __float2bfloat16(f);
  return *reinterpret_cast<u16*>(&h);
}
static __device__ __forceinline__ float bf2f(u16 u) {
  union { unsigned int i; float f; } v; v.i = ((unsigned int)u) << 16; return v.f;
}
static __device__ __forceinline__ void gl_lds16(const void* g, void* l) {
  __builtin_amdgcn_global_load_lds((const __attribute__((address_space(1))) void*)g,
                                   (__attribute__((address_space(3))) void*)l, 16, 0, 0);
}
static __device__ __forceinline__ f32x16 zero16() {
  f32x16 v;
#pragma unroll
  for (int i = 0; i < 16; ++i) v[i] = 0.f;
  return v;
}
static __device__ __forceinline__ unsigned cvtpk(float lo, float hi_) {
  unsigned r;
  asm("v_cvt_pk_bf16_f32 %0, %1, %2" : "=v"(r) : "v"(lo), "v"(hi_));
  return r;
}
static __device__ __forceinline__ void pl32swap(unsigned &a, unsigned &b) {
  asm("v_permlane32_swap_b32 %0, %1" : "+v"(a), "+v"(b));
}
static __device__ __forceinline__ bf16x8 frag4(unsigned w0, unsigned w1,
                                               unsigned w2, unsigned w3) {
  union { u32x4 w; bf16x8 h; } u;
  u.w[0] = w0; u.w[1] = w1; u.w[2] = w2; u.w[3] = w3;
  return u.h;
}

// ---------------- Kernel 1: projections theta/phi -> [b][n][ic], g -> [b][ic][n] ----
// grid: BB * (NN/32) = 512 blocks, 256 threads
__global__ __launch_bounds__(256) void proj_kernel(
    const float* __restrict__ x,
    const float* __restrict__ gw, const float* __restrict__ gb,
    const float* __restrict__ tw, const float* __restrict__ tb,
    const float* __restrict__ pw, const float* __restrict__ pb,
    u16* __restrict__ th, u16* __restrict__ ph, u16* __restrict__ gt)
{
  __shared__ float xs[CC][32];
  __shared__ u16 gs[64][34];
  const int b  = blockIdx.x >> 7;
  const int n0 = (blockIdx.x & 127) << 5;
  const int t  = threadIdx.x;

  for (int idx = t; idx < CC * 32; idx += 256) {
    int c = idx >> 5, n = idx & 31;
    xs[c][n] = x[((size_t)(b * CC + c) << 12) + n0 + n];
  }
  __syncthreads();

  const int ic = t & 63;
  const int nb = t >> 6;  // 0..3
  float ag[8], at[8], ap[8];
#pragma unroll
  for (int j = 0; j < 8; ++j) { ag[j] = 0.f; at[j] = 0.f; ap[j] = 0.f; }

  const float4* gw4 = (const float4*)(gw + ic * CC);
  const float4* tw4 = (const float4*)(tw + ic * CC);
  const float4* pw4 = (const float4*)(pw + ic * CC);
#pragma unroll 2
  for (int c4 = 0; c4 < CC / 4; ++c4) {
    float4 wg = gw4[c4], wt = tw4[c4], wp = pw4[c4];
#pragma unroll
    for (int cc = 0; cc < 4; ++cc) {
      float wgv = (&wg.x)[cc], wtv = (&wt.x)[cc], wpv = (&wp.x)[cc];
      int c = c4 * 4 + cc;
#pragma unroll
      for (int j = 0; j < 8; ++j) {
        float xv = xs[c][nb + 4 * j];
        ag[j] = fmaf(wgv, xv, ag[j]);
        at[j] = fmaf(wtv, xv, at[j]);
        ap[j] = fmaf(wpv, xv, ap[j]);
      }
    }
  }
  const float bgv = gb[ic], btv = tb[ic], bpv = pb[ic];
#pragma unroll
  for (int j = 0; j < 8; ++j) {
    int n = n0 + nb + 4 * j;
    size_t o = ((size_t)(b * NN + n)) * ICH + ic;
    th[o] = f2bf(at[j] + btv);
    ph[o] = f2bf(ap[j] + bpv);
    gs[ic][nb + 4 * j] = f2bf(ag[j] + bgv);
  }
  __syncthreads();
  {
    const int row = t >> 2, ch = t & 3;
    u16 tmp[8];
#pragma unroll
    for (int j = 0; j < 8; ++j) tmp[j] = gs[row][ch * 8 + j];
    size_t go = ((size_t)(b * ICH + row)) * NN + n0 + ch * 8;
    *(bf16x8*)(gt + go) = *(bf16x8*)tmp;
  }
}

// ---------------- Kernel 2: flash attention, swapped operands, in-register P --------
// grid: BB * (NN/256) * SS = 512 blocks, 256 threads (4 waves x 64 query rows)
__global__ __launch_bounds__(256) void attn_kernel(
    const u16* __restrict__ thp, const u16* __restrict__ php,
    const u16* __restrict__ gtp, u16* __restrict__ yp, float* __restrict__ Lq)
{
  __shared__ __align__(16) u16 ph_s[2][4096];  // [buf][64 keys][64 ic], 128B rows, swz
  __shared__ __align__(16) u16 gt_s[2][4096];  // [buf][64 ic][64 keys], 128B rows, swz

  const int t    = threadIdx.x;
  const int wave = t >> 6, lane = t & 63;
  const int l31  = lane & 31, hi = lane >> 5;
  const int bid  = blockIdx.x;
  const int s    = bid & 7;
  const int rb   = (bid >> 3) & 15;
  const int b    = bid >> 7;
  const int nwb  = rb * 256 + wave * 64;      // wave's first query row
  const size_t bbase = (size_t)b * NN * ICH;

  const int swz  = (l31 & 7) << 4;
  const int koff = 16 * ((lane & 7) ^ (lane >> 3));

  // theta B-fragments (held whole kernel): col q = nwb + cb*32 + l31, k-slice ks*16+hi*8
  bf16x8 aq[2][4];
#pragma unroll
  for (int cb = 0; cb < 2; ++cb)
#pragma unroll
    for (int ks = 0; ks < 4; ++ks)
      aq[cb][ks] = *(const bf16x8*)(thp + bbase +
                    (size_t)(nwb + cb * 32 + l31) * ICH + ks * 16 + hi * 8);

  f32x16 yacc[2][2];  // [colblock][ci]
  yacc[0][0] = zero16(); yacc[0][1] = zero16();
  yacc[1][0] = zero16(); yacc[1][1] = zero16();
  float Lp[2] = {0.f, 0.f};

  const char* ph_g = (const char*)php + bbase * 2;
  const char* gt_g = (const char*)gtp + (size_t)b * ICH * NN * 2;
  const int m_start = s * KSPLIT;

  auto stage = [&](int mt, int buf) {
    const int m0 = m_start + mt * 64;
#pragma unroll
    for (int u = 0; u < 2; ++u) {
      const int kk = wave * 2 + u;
      const int row = kk * 8 + (lane >> 3);
      gl_lds16(ph_g + (size_t)(m0 + row) * 128 + koff, (char*)ph_s[buf] + kk * 1024);
      gl_lds16(gt_g + (size_t)row * (NN * 2) + m0 * 2 + koff, (char*)gt_s[buf] + kk * 1024);
    }
  };

  stage(0, 0);
  for (int mt = 0; mt < MT; ++mt) {
    __syncthreads();                     // staged tile mt visible (vmcnt drained)
    if (mt + 1 < MT) stage(mt + 1, (mt + 1) & 1);
    const char* phb = (const char*)ph_s[mt & 1];
    const char* gtb = (const char*)gt_s[mt & 1];

#pragma unroll
    for (int c = 0; c < 2; ++c) {        // key chunks of 32
      // S^T = phi . theta^T : A-frag = phi rows (keys), shared across colblocks
      bf16x8 pf4[4];
#pragma unroll
      for (int ks = 0; ks < 4; ++ks)
        pf4[ks] = *(const bf16x8*)(phb + (c * 32 + l31) * 128 +
                                   ((ks * 32 + hi * 16) ^ swz));
      f32x16 sacc[2];
      sacc[0] = zero16(); sacc[1] = zero16();
#pragma unroll
      for (int ks = 0; ks < 4; ++ks) {
        sacc[0] = mfma32(pf4[ks], aq[0][ks], sacc[0]);
        sacc[1] = mfma32(pf4[ks], aq[1][ks], sacc[1]);
      }

      // softmax + in-register P fragments (cvt_pk + permlane32_swap)
      unsigned pk[2][8];   // [cb][km*4 + word]
#pragma unroll
      for (int cb = 0; cb < 2; ++cb) {
        float p[16];
#pragma unroll
        for (int r = 0; r < 16; ++r) {
          p[r] = __expf(sacc[cb][r] - 8.0f);
          Lp[cb] += p[r];
        }
#pragma unroll
        for (int km = 0; km < 2; ++km) {
          unsigned P0 = cvtpk(p[km * 8 + 0], p[km * 8 + 1]);
          unsigned P1 = cvtpk(p[km * 8 + 2], p[km * 8 + 3]);
          unsigned P2 = cvtpk(p[km * 8 + 4], p[km * 8 + 5]);
          unsigned P3 = cvtpk(p[km * 8 + 6], p[km * 8 + 7]);
          pl32swap(P0, P2);
          pl32swap(P1, P3);
          pk[cb][km * 4 + 0] = P0; pk[cb][km * 4 + 1] = P1;
          pk[cb][km * 4 + 2] = P2; pk[cb][km * 4 + 3] = P3;
        }
      }

      // PV: y^T = g^T . P^T ; g A-frag shared across colblocks
#pragma unroll
      for (int ci = 0; ci < 2; ++ci) {
        bf16x8 gA[2];
#pragma unroll
        for (int km = 0; km < 2; ++km)
          gA[km] = *(const bf16x8*)(gtb + (ci * 32 + l31) * 128 +
                                    ((c * 64 + km * 32 + hi * 16) ^ swz));
#pragma unroll
        for (int cb = 0; cb < 2; ++cb) {
          yacc[cb][ci] = mfma32(gA[0], frag4(pk[cb][0], pk[cb][1], pk[cb][2], pk[cb][3]), yacc[cb][ci]);
          yacc[cb][ci] = mfma32(gA[1], frag4(pk[cb][4], pk[cb][5], pk[cb][6], pk[cb][7]), yacc[cb][ci]);
        }
      }
    }
  }

  // L: own 16-key partials + partner half
  Lp[0] += __shfl_xor(Lp[0], 32);
  Lp[1] += __shfl_xor(Lp[1], 32);

  const size_t pbase = ((size_t)s * BB + b) * NN;
  if (hi == 0) Lq[pbase + nwb + l31]      = Lp[0];
  else         Lq[pbase + nwb + 32 + l31] = Lp[1];

#pragma unroll
  for (int cb = 0; cb < 2; ++cb) {
    const size_t qg = pbase + nwb + cb * 32 + l31;
#pragma unroll
    for (int ci = 0; ci < 2; ++ci)
#pragma unroll
      for (int rg = 0; rg < 4; ++rg) {
        u16 o4[4];
#pragma unroll
        for (int j = 0; j < 4; ++j) o4[j] = f2bf(yacc[cb][ci][rg * 4 + j]);
        *(unsigned long long*)(yp + qg * ICH + ci * 32 + 8 * rg + 4 * hi) =
            *(unsigned long long*)o4;
      }
  }
}

// ---------------- Kernel 3: combine partials, out = W.y + Wb + x (MFMA) -------------
// grid: BB * (NN/32) = 512 blocks, 256 threads (4 waves x 32 c-rows)
__global__ __launch_bounds__(256) void out_kernel(
    const float* __restrict__ x, const float* __restrict__ Ww,
    const float* __restrict__ Wb, const u16* __restrict__ yp,
    const float* __restrict__ Lq, float* __restrict__ out)
{
  __shared__ __align__(16) u16 ys[4096];   // [32 n][64 ic] bf16, 128B rows, swz
  const int t = threadIdx.x, lane = t & 63;
  const int wave = t >> 6, l31 = lane & 31, hi = lane >> 5;
  const int b  = blockIdx.x >> 7;
  const int n0 = (blockIdx.x & 127) << 5;

  // phase 0: combine the SS partials -> normalized y (bf16) in LDS
  {
    const int n = t >> 3, i8 = t & 7;
    float den = 0.f;
#pragma unroll
    for (int s = 0; s < SS; ++s) den += Lq[((size_t)s * BB + b) * NN + n0 + n];
    float num[8];
#pragma unroll
    for (int j = 0; j < 8; ++j) num[j] = 0.f;
#pragma unroll
    for (int s = 0; s < SS; ++s) {
      bf16x8 v = *(const bf16x8*)(yp + (((size_t)s * BB + b) * NN + n0 + n) * ICH + i8 * 8);
#pragma unroll
      for (int j = 0; j < 8; ++j) num[j] += bf2f((u16)v[j]);
    }
    float rd = 1.f / den;
    u16 o[8];
#pragma unroll
    for (int j = 0; j < 8; ++j) o[j] = f2bf(num[j] * rd);
    *(bf16x8*)((char*)ys + n * 128 + ((i8 * 16) ^ ((n & 7) << 4))) = *(bf16x8*)o;
  }
  __syncthreads();

  // phase 1: W.y via MFMA; wave handles c-chunk wave*32
  f32x16 acc = zero16();
  const int crow = wave * 32 + l31;
#pragma unroll
  for (int ks = 0; ks < 4; ++ks) {
    const float* wp = Ww + crow * ICH + ks * 16 + hi * 8;
    float4 w0 = *(const float4*)wp, w1 = *(const float4*)(wp + 4);
    u16 af[8];
    af[0] = f2bf(w0.x); af[1] = f2bf(w0.y); af[2] = f2bf(w0.z); af[3] = f2bf(w0.w);
    af[4] = f2bf(w1.x); af[5] = f2bf(w1.y); af[6] = f2bf(w1.z); af[7] = f2bf(w1.w);
    bf16x8 bf = *(const bf16x8*)((char*)ys + l31 * 128 +
                                 ((ks * 32 + hi * 16) ^ ((l31 & 7) << 4)));
    acc = mfma32(*(const bf16x8*)af, bf, acc);
  }
#pragma unroll
  for (int reg = 0; reg < 16; ++reg) {
    const int c = wave * 32 + (reg & 3) + 8 * (reg >> 2) + 4 * hi;
    size_t o = ((size_t)(b * CC + c) << 12) + n0 + l31;
    out[o] = acc[reg] + Wb[c] + x[o];
  }
}

extern "C" void kernel_launch(void* const* d_in, const int* in_sizes, int n_in,
                              void* d_out, int out_size, void* d_ws, size_t ws_size,
                              hipStream_t stream) {
  const float* x  = (const float*)d_in[0];
  const float* gw = (const float*)d_in[1];
  const float* gb = (const float*)d_in[2];
  const float* tw = (const float*)d_in[3];
  const float* tb = (const float*)d_in[4];
  const float* pw = (const float*)d_in[5];
  const float* pb = (const float*)d_in[6];
  const float* Ww = (const float*)d_in[7];
  const float* Wb = (const float*)d_in[8];
  float* out = (float*)d_out;

  char* ws = (char*)d_ws;
  u16*   th = (u16*)(ws);                      // 2MB
  u16*   ph = (u16*)(ws + (2ull << 20));       // 2MB
  u16*   gt = (u16*)(ws + (4ull << 20));       // 2MB
  u16*   yp = (u16*)(ws + (6ull << 20));       // SS*B*N*IC bf16 = 16MB
  float* Lq = (float*)(ws + (22ull << 20));    // SS*B*N f32 = 512KB

  proj_kernel<<<512, 256, 0, stream>>>(x, gw, gb, tw, tb, pw, pb, th, ph, gt);
  attn_kernel<<<BB * (NN / 256) * SS, 256, 0, stream>>>(th, ph, gt, yp, Lq);
  out_kernel<<<512, 256, 0, stream>>>(x, Ww, Wb, yp, Lq, out);
}

// Round 6
// 78.682 us; speedup vs baseline: 1.1131x; 1.1131x over previous
//
#include <hip/hip_runtime.h>
#include <hip/hip_bf16.h>

#define BB  4
#define CC  128
#define ICH 64
#define NN  4096
#define SS  8            // KV split factor
#define KSPLIT (NN / SS) // 512 keys per block
#define MT (KSPLIT / 64) // 8 key-tiles per block

typedef __attribute__((ext_vector_type(4)))  float f32x4;
typedef __attribute__((ext_vector_type(16))) float f32x16;
typedef __attribute__((ext_vector_type(8)))  short bf16x8;
typedef __attribute__((ext_vector_type(4)))  unsigned u32x4;
typedef unsigned short u16;

static __device__ __forceinline__ f32x16 mfma32(bf16x8 a, bf16x8 b, f32x16 c) {
  return __builtin_amdgcn_mfma_f32_32x32x16_bf16(a, b, c, 0, 0, 0);
}
static __device__ __forceinline__ u16 f2bf(float f) {
  __hip_bfloat16 h = __float2bfloat16(f);
  return *reinterpret_cast<u16*>(&h);
}
static __device__ __forceinline__ float bf2f(u16 u) {
  union { unsigned int i; float f; } v; v.i = ((unsigned int)u) << 16; return v.f;
}
static __device__ __forceinline__ void gl_lds16(const void* g, void* l) {
  __builtin_amdgcn_global_load_lds((const __attribute__((address_space(1))) void*)g,
                                   (__attribute__((address_space(3))) void*)l, 16, 0, 0);
}
static __device__ __forceinline__ f32x16 zero16() {
  f32x16 v;
#pragma unroll
  for (int i = 0; i < 16; ++i) v[i] = 0.f;
  return v;
}
static __device__ __forceinline__ unsigned cvtpk(float lo, float hi_) {
  unsigned r;
  asm("v_cvt_pk_bf16_f32 %0, %1, %2" : "=v"(r) : "v"(lo), "v"(hi_));
  return r;
}
static __device__ __forceinline__ void pl32swap(unsigned &a, unsigned &b) {
  asm("v_permlane32_swap_b32 %0, %1" : "+v"(a), "+v"(b));
}
static __device__ __forceinline__ bf16x8 frag4(unsigned w0, unsigned w1,
                                               unsigned w2, unsigned w3) {
  union { u32x4 w; bf16x8 h; } u;
  u.w[0] = w0; u.w[1] = w1; u.w[2] = w2; u.w[3] = w3;
  return u.h;
}

// ---------------- Kernel 1: projections theta/phi -> [b][n][ic], g -> [b][ic][n] ----
// (R4 verbatim — validated) grid: BB * (NN/32) = 512 blocks, 256 threads
__global__ __launch_bounds__(256) void proj_kernel(
    const float* __restrict__ x,
    const float* __restrict__ gw, const float* __restrict__ gb,
    const float* __restrict__ tw, const float* __restrict__ tb,
    const float* __restrict__ pw, const float* __restrict__ pb,
    u16* __restrict__ th, u16* __restrict__ ph, u16* __restrict__ gt)
{
  __shared__ float xs[CC][32];
  __shared__ u16 gs[64][34];
  const int b  = blockIdx.x >> 7;
  const int n0 = (blockIdx.x & 127) << 5;
  const int t  = threadIdx.x;

  for (int idx = t; idx < CC * 32; idx += 256) {
    int c = idx >> 5, n = idx & 31;
    xs[c][n] = x[((size_t)(b * CC + c) << 12) + n0 + n];
  }
  __syncthreads();

  const int ic = t & 63;
  const int nb = t >> 6;  // 0..3
  float ag[8], at[8], ap[8];
#pragma unroll
  for (int j = 0; j < 8; ++j) { ag[j] = 0.f; at[j] = 0.f; ap[j] = 0.f; }

  const float4* gw4 = (const float4*)(gw + ic * CC);
  const float4* tw4 = (const float4*)(tw + ic * CC);
  const float4* pw4 = (const float4*)(pw + ic * CC);
#pragma unroll 2
  for (int c4 = 0; c4 < CC / 4; ++c4) {
    float4 wg = gw4[c4], wt = tw4[c4], wp = pw4[c4];
#pragma unroll
    for (int cc = 0; cc < 4; ++cc) {
      float wgv = (&wg.x)[cc], wtv = (&wt.x)[cc], wpv = (&wp.x)[cc];
      int c = c4 * 4 + cc;
#pragma unroll
      for (int j = 0; j < 8; ++j) {
        float xv = xs[c][nb + 4 * j];
        ag[j] = fmaf(wgv, xv, ag[j]);
        at[j] = fmaf(wtv, xv, at[j]);
        ap[j] = fmaf(wpv, xv, ap[j]);
      }
    }
  }
  const float bgv = gb[ic], btv = tb[ic], bpv = pb[ic];
#pragma unroll
  for (int j = 0; j < 8; ++j) {
    int n = n0 + nb + 4 * j;
    size_t o = ((size_t)(b * NN + n)) * ICH + ic;
    th[o] = f2bf(at[j] + btv);
    ph[o] = f2bf(ap[j] + bpv);
    gs[ic][nb + 4 * j] = f2bf(ag[j] + bgv);
  }
  __syncthreads();
  {
    const int row = t >> 2, ch = t & 3;
    u16 tmp[8];
#pragma unroll
    for (int j = 0; j < 8; ++j) tmp[j] = gs[row][ch * 8 + j];
    size_t go = ((size_t)(b * ICH + row)) * NN + n0 + ch * 8;
    *(bf16x8*)(gt + go) = *(bf16x8*)tmp;
  }
}

// ---------------- Kernel 2: flash attention, swapped operands, in-register P --------
// grid: BB * (NN/128) * SS = 1024 blocks, 256 threads (4 waves x 32 query rows)
__global__ __launch_bounds__(256, 4) void attn_kernel(
    const u16* __restrict__ thp, const u16* __restrict__ php,
    const u16* __restrict__ gtp, u16* __restrict__ yp, float* __restrict__ Lq)
{
  __shared__ __align__(16) u16 ph_s[2][4096];  // [buf][64 keys][64 ic], 128B rows, swz
  __shared__ __align__(16) u16 gt_s[2][4096];  // [buf][64 ic][64 keys], 128B rows, swz

  const int t    = threadIdx.x;
  const int wave = t >> 6, lane = t & 63;
  const int l31  = lane & 31, hi = lane >> 5;
  const int bid  = blockIdx.x;
  const int s    = bid & 7;
  const int rb   = (bid >> 3) & 31;
  const int b    = bid >> 8;
  const int nw   = rb * 128 + wave * 32;      // wave's first query row
  const size_t bbase = (size_t)b * NN * ICH;

  const int swz  = (l31 & 7) << 4;
  const int koff = 16 * ((lane & 7) ^ (lane >> 3));

  // theta B-fragments (held whole kernel): col q = nw + l31, k-slice ks*16 + hi*8
  bf16x8 aq[4];
#pragma unroll
  for (int ks = 0; ks < 4; ++ks)
    aq[ks] = *(const bf16x8*)(thp + bbase + (size_t)(nw + l31) * ICH + ks * 16 + hi * 8);

  f32x16 yacc[2];
  yacc[0] = zero16(); yacc[1] = zero16();
  float Lp = 0.f;

  const char* ph_g = (const char*)php + bbase * 2;
  const char* gt_g = (const char*)gtp + (size_t)b * ICH * NN * 2;
  const int m_start = s * KSPLIT;

  auto stage = [&](int mt, int buf) {
    const int m0 = m_start + mt * 64;
#pragma unroll
    for (int u = 0; u < 2; ++u) {
      const int kk = wave * 2 + u;
      const int row = kk * 8 + (lane >> 3);
      gl_lds16(ph_g + (size_t)(m0 + row) * 128 + koff, (char*)ph_s[buf] + kk * 1024);
      gl_lds16(gt_g + (size_t)row * (NN * 2) + m0 * 2 + koff, (char*)gt_s[buf] + kk * 1024);
    }
  };

  stage(0, 0);
  for (int mt = 0; mt < MT; ++mt) {
    __syncthreads();                     // staged tile mt visible (vmcnt drained)
    if (mt + 1 < MT) stage(mt + 1, (mt + 1) & 1);
    const char* phb = (const char*)ph_s[mt & 1];
    const char* gtb = (const char*)gt_s[mt & 1];

#pragma unroll
    for (int c = 0; c < 2; ++c) {        // key chunks of 32
      // S^T = phi . theta^T : A-frag = phi rows (keys)
      bf16x8 pf4[4];
#pragma unroll
      for (int ks = 0; ks < 4; ++ks)
        pf4[ks] = *(const bf16x8*)(phb + (c * 32 + l31) * 128 +
                                   ((ks * 32 + hi * 16) ^ swz));
      f32x16 sacc = zero16();
#pragma unroll
      for (int ks = 0; ks < 4; ++ks)
        sacc = mfma32(pf4[ks], aq[ks], sacc);

      // softmax + in-register P fragments (cvt_pk + permlane32_swap)
      float p[16];
#pragma unroll
      for (int r = 0; r < 16; ++r) {
        p[r] = __expf(sacc[r] - 8.0f);
        Lp += p[r];
      }
      unsigned pk[8];
#pragma unroll
      for (int km = 0; km < 2; ++km) {
        unsigned P0 = cvtpk(p[km * 8 + 0], p[km * 8 + 1]);
        unsigned P1 = cvtpk(p[km * 8 + 2], p[km * 8 + 3]);
        unsigned P2 = cvtpk(p[km * 8 + 4], p[km * 8 + 5]);
        unsigned P3 = cvtpk(p[km * 8 + 6], p[km * 8 + 7]);
        pl32swap(P0, P2);
        pl32swap(P1, P3);
        pk[km * 4 + 0] = P0; pk[km * 4 + 1] = P1;
        pk[km * 4 + 2] = P2; pk[km * 4 + 3] = P3;
      }
      bf16x8 pB0 = frag4(pk[0], pk[1], pk[2], pk[3]);
      bf16x8 pB1 = frag4(pk[4], pk[5], pk[6], pk[7]);

      // PV: y^T = g^T . P^T
#pragma unroll
      for (int ci = 0; ci < 2; ++ci) {
        bf16x8 gA0 = *(const bf16x8*)(gtb + (ci * 32 + l31) * 128 +
                                      ((c * 64 + 0  + hi * 16) ^ swz));
        bf16x8 gA1 = *(const bf16x8*)(gtb + (ci * 32 + l31) * 128 +
                                      ((c * 64 + 32 + hi * 16) ^ swz));
        yacc[ci] = mfma32(gA0, pB0, yacc[ci]);
        yacc[ci] = mfma32(gA1, pB1, yacc[ci]);
      }
    }
  }

  // L: own 16-key partials + partner half
  Lp += __shfl_xor(Lp, 32);

  const size_t pbase = ((size_t)s * BB + b) * NN;
  if (hi == 0) Lq[pbase + nw + l31] = Lp;

  const size_t qg = pbase + nw + l31;
#pragma unroll
  for (int ci = 0; ci < 2; ++ci)
#pragma unroll
    for (int rg = 0; rg < 4; ++rg) {
      u16 o4[4];
#pragma unroll
      for (int j = 0; j < 4; ++j) o4[j] = f2bf(yacc[ci][rg * 4 + j]);
      *(unsigned long long*)(yp + qg * ICH + ci * 32 + 8 * rg + 4 * hi) =
          *(unsigned long long*)o4;
    }
}

// ---------------- Kernel 3: combine partials, out = W.y + Wb + x (MFMA) -------------
// (R4 verbatim — validated) grid: BB * (NN/32) = 512 blocks, 256 threads
__global__ __launch_bounds__(256) void out_kernel(
    const float* __restrict__ x, const float* __restrict__ Ww,
    const float* __restrict__ Wb, const u16* __restrict__ yp,
    const float* __restrict__ Lq, float* __restrict__ out)
{
  __shared__ __align__(16) u16 ys[4096];   // [32 n][64 ic] bf16, 128B rows, swz
  const int t = threadIdx.x, lane = t & 63;
  const int wave = t >> 6, l31 = lane & 31, hi = lane >> 5;
  const int b  = blockIdx.x >> 7;
  const int n0 = (blockIdx.x & 127) << 5;

  // phase 0: combine the SS partials -> normalized y (bf16) in LDS
  {
    const int n = t >> 3, i8 = t & 7;
    float den = 0.f;
#pragma unroll
    for (int s = 0; s < SS; ++s) den += Lq[((size_t)s * BB + b) * NN + n0 + n];
    float num[8];
#pragma unroll
    for (int j = 0; j < 8; ++j) num[j] = 0.f;
#pragma unroll
    for (int s = 0; s < SS; ++s) {
      bf16x8 v = *(const bf16x8*)(yp + (((size_t)s * BB + b) * NN + n0 + n) * ICH + i8 * 8);
#pragma unroll
      for (int j = 0; j < 8; ++j) num[j] += bf2f((u16)v[j]);
    }
    float rd = 1.f / den;
    u16 o[8];
#pragma unroll
    for (int j = 0; j < 8; ++j) o[j] = f2bf(num[j] * rd);
    *(bf16x8*)((char*)ys + n * 128 + ((i8 * 16) ^ ((n & 7) << 4))) = *(bf16x8*)o;
  }
  __syncthreads();

  // phase 1: W.y via MFMA; wave handles c-chunk wave*32
  f32x16 acc = zero16();
  const int crow = wave * 32 + l31;
#pragma unroll
  for (int ks = 0; ks < 4; ++ks) {
    const float* wp = Ww + crow * ICH + ks * 16 + hi * 8;
    float4 w0 = *(const float4*)wp, w1 = *(const float4*)(wp + 4);
    u16 af[8];
    af[0] = f2bf(w0.x); af[1] = f2bf(w0.y); af[2] = f2bf(w0.z); af[3] = f2bf(w0.w);
    af[4] = f2bf(w1.x); af[5] = f2bf(w1.y); af[6] = f2bf(w1.z); af[7] = f2bf(w1.w);
    bf16x8 bf = *(const bf16x8*)((char*)ys + l31 * 128 +
                                 ((ks * 32 + hi * 16) ^ ((l31 & 7) << 4)));
    acc = mfma32(*(const bf16x8*)af, bf, acc);
  }
#pragma unroll
  for (int reg = 0; reg < 16; ++reg) {
    const int c = wave * 32 + (reg & 3) + 8 * (reg >> 2) + 4 * hi;
    size_t o = ((size_t)(b * CC + c) << 12) + n0 + l31;
    out[o] = acc[reg] + Wb[c] + x[o];
  }
}

extern "C" void kernel_launch(void* const* d_in, const int* in_sizes, int n_in,
                              void* d_out, int out_size, void* d_ws, size_t ws_size,
                              hipStream_t stream) {
  const float* x  = (const float*)d_in[0];
  const float* gw = (const float*)d_in[1];
  const float* gb = (const float*)d_in[2];
  const float* tw = (const float*)d_in[3];
  const float* tb = (const float*)d_in[4];
  const float* pw = (const float*)d_in[5];
  const float* pb = (const float*)d_in[6];
  const float* Ww = (const float*)d_in[7];
  const float* Wb = (const float*)d_in[8];
  float* out = (float*)d_out;

  char* ws = (char*)d_ws;
  u16*   th = (u16*)(ws);                      // 2MB
  u16*   ph = (u16*)(ws + (2ull << 20));       // 2MB
  u16*   gt = (u16*)(ws + (4ull << 20));       // 2MB
  u16*   yp = (u16*)(ws + (6ull << 20));       // SS*B*N*IC bf16 = 16MB
  float* Lq = (float*)(ws + (22ull << 20));    // SS*B*N f32 = 512KB

  proj_kernel<<<512, 256, 0, stream>>>(x, gw, gb, tw, tb, pw, pb, th, ph, gt);
  attn_kernel<<<BB * (NN / 128) * SS, 256, 0, stream>>>(th, ph, gt, yp, Lq);
  out_kernel<<<512, 256, 0, stream>>>(x, Ww, Wb, yp, Lq, out);
}

// Round 7
// 57.766 us; speedup vs baseline: 1.5161x; 1.3621x over previous
//
#include <hip/hip_runtime.h>
#include <hip/hip_bf16.h>

#define BB  4
#define CC  128
#define ICH 64
#define NN  4096
#define SS  8            // KV split factor
#define KSPLIT (NN / SS) // 512 keys per block
#define MT (KSPLIT / 64) // 8 key-tiles per block

typedef __attribute__((ext_vector_type(4)))  float f32x4;
typedef __attribute__((ext_vector_type(16))) float f32x16;
typedef __attribute__((ext_vector_type(8)))  short bf16x8;
typedef __attribute__((ext_vector_type(4)))  unsigned u32x4;
typedef unsigned short u16;

static __device__ __forceinline__ f32x16 mfma32(bf16x8 a, bf16x8 b, f32x16 c) {
  return __builtin_amdgcn_mfma_f32_32x32x16_bf16(a, b, c, 0, 0, 0);
}
static __device__ __forceinline__ u16 f2bf(float f) {
  __hip_bfloat16 h = __float2bfloat16(f);
  return *reinterpret_cast<u16*>(&h);
}
static __device__ __forceinline__ float bf2f(u16 u) {
  union { unsigned int i; float f; } v; v.i = ((unsigned int)u) << 16; return v.f;
}
static __device__ __forceinline__ void gl_lds16(const void* g, void* l) {
  __builtin_amdgcn_global_load_lds((const __attribute__((address_space(1))) void*)g,
                                   (__attribute__((address_space(3))) void*)l, 16, 0, 0);
}
static __device__ __forceinline__ f32x16 zero16() {
  f32x16 v;
#pragma unroll
  for (int i = 0; i < 16; ++i) v[i] = 0.f;
  return v;
}
static __device__ __forceinline__ unsigned cvtpk(float lo, float hi_) {
  unsigned r;
  asm("v_cvt_pk_bf16_f32 %0, %1, %2" : "=v"(r) : "v"(lo), "v"(hi_));
  return r;
}
static __device__ __forceinline__ void pl32swap(unsigned &a, unsigned &b) {
  asm("v_permlane32_swap_b32 %0, %1" : "+v"(a), "+v"(b));
}
static __device__ __forceinline__ bf16x8 frag4(unsigned w0, unsigned w1,
                                               unsigned w2, unsigned w3) {
  union { u32x4 w; bf16x8 h; } u;
  u.w[0] = w0; u.w[1] = w1; u.w[2] = w2; u.w[3] = w3;
  return u.h;
}

// ---------------- Kernel 1: projections via MFMA ------------------------------------
// grid: BB * (NN/32) = 512 blocks, 384 threads (6 waves).
// wave -> (proj type pt = wave>>1, ic half ic0 = (wave&1)*32)
// pt==0: g  -> D[ic][n] (A=W, B=X)  -> gt [b][ic][n]
// pt==1/2: theta/phi -> D[n][ic] (A=X^T, B=W^T) -> th/ph [b][n][ic]
__global__ __launch_bounds__(384) void proj_kernel(
    const float* __restrict__ x,
    const float* __restrict__ gw, const float* __restrict__ gb,
    const float* __restrict__ tw, const float* __restrict__ tb,
    const float* __restrict__ pw, const float* __restrict__ pb,
    u16* __restrict__ th, u16* __restrict__ ph, u16* __restrict__ gt)
{
  __shared__ __align__(16) float xs[CC * 32];   // [c][32 n], 128B rows
  const int t = threadIdx.x, wave = t / 64, lane = t & 63;
  const int l31 = lane & 31, hi = lane >> 5;
  const int b  = blockIdx.x >> 7;
  const int n0 = (blockIdx.x & 127) << 5;

  // stage x tile [128 c][32 n] f32 (16KB) via plain vector loads
  for (int idx = t; idx < CC * 8; idx += 384) {   // 1024 float4 chunks
    const int c = idx >> 3, n4 = idx & 7;
    *(float4*)&xs[c * 32 + n4 * 4] =
        *(const float4*)(x + ((size_t)(b * CC + c) << 12) + n0 + n4 * 4);
  }

  const int pt  = wave >> 1;
  const int ic0 = (wave & 1) << 5;
  const float* wsel = (pt == 0) ? gw : (pt == 1) ? tw : pw;

  // weight fragments: A-row / B-col = ic0 + l31, k-slot (hi,j) <-> c = ks*16 + hi*8 + j
  bf16x8 wfrag[8];
  {
    const float* wrow = wsel + (ic0 + l31) * CC;
#pragma unroll
    for (int ks = 0; ks < 8; ++ks) {
      float4 a = *(const float4*)(wrow + ks * 16 + hi * 8);
      float4 c = *(const float4*)(wrow + ks * 16 + hi * 8 + 4);
      wfrag[ks] = frag4(cvtpk(a.x, a.y), cvtpk(a.z, a.w),
                        cvtpk(c.x, c.y), cvtpk(c.z, c.w));
    }
  }
  __syncthreads();

  // x fragments from LDS (bank = n -> conflict-free broadcast reads) + MFMA
  f32x16 acc = zero16();
  if (pt == 0) {
#pragma unroll
    for (int ks = 0; ks < 8; ++ks) {
      const float* xp = xs + (ks * 16 + hi * 8) * 32 + l31;
      bf16x8 xf = frag4(cvtpk(xp[0], xp[32]),   cvtpk(xp[64], xp[96]),
                        cvtpk(xp[128], xp[160]), cvtpk(xp[192], xp[224]));
      acc = mfma32(wfrag[ks], xf, acc);
    }
    // D[ic][n]: col = n0+l31, row (reg-mapped) = ic
#pragma unroll
    for (int reg = 0; reg < 16; ++reg) {
      const int ic = ic0 + (reg & 3) + 8 * (reg >> 2) + 4 * hi;
      gt[((size_t)(b * ICH + ic)) * NN + n0 + l31] = f2bf(acc[reg] + gb[ic]);
    }
  } else {
#pragma unroll
    for (int ks = 0; ks < 8; ++ks) {
      const float* xp = xs + (ks * 16 + hi * 8) * 32 + l31;
      bf16x8 xf = frag4(cvtpk(xp[0], xp[32]),   cvtpk(xp[64], xp[96]),
                        cvtpk(xp[128], xp[160]), cvtpk(xp[192], xp[224]));
      acc = mfma32(xf, wfrag[ks], acc);
    }
    u16* dst = (pt == 1) ? th : ph;
    const float bias = (pt == 1) ? tb[ic0 + l31] : pb[ic0 + l31];
    // D[n][ic]: col = ic0+l31, row (reg-mapped) = n
#pragma unroll
    for (int reg = 0; reg < 16; ++reg) {
      const int n = n0 + (reg & 3) + 8 * (reg >> 2) + 4 * hi;
      dst[((size_t)(b * NN + n)) * ICH + ic0 + l31] = f2bf(acc[reg] + bias);
    }
  }
}

// ---------------- Kernel 2: flash attention (R6 verbatim — validated) ---------------
// grid: BB * (NN/128) * SS = 1024 blocks, 256 threads (4 waves x 32 query rows)
__global__ __launch_bounds__(256, 4) void attn_kernel(
    const u16* __restrict__ thp, const u16* __restrict__ php,
    const u16* __restrict__ gtp, u16* __restrict__ yp, float* __restrict__ Lq)
{
  __shared__ __align__(16) u16 ph_s[2][4096];  // [buf][64 keys][64 ic], 128B rows, swz
  __shared__ __align__(16) u16 gt_s[2][4096];  // [buf][64 ic][64 keys], 128B rows, swz

  const int t    = threadIdx.x;
  const int wave = t >> 6, lane = t & 63;
  const int l31  = lane & 31, hi = lane >> 5;
  const int bid  = blockIdx.x;
  const int s    = bid & 7;
  const int rb   = (bid >> 3) & 31;
  const int b    = bid >> 8;
  const int nw   = rb * 128 + wave * 32;      // wave's first query row
  const size_t bbase = (size_t)b * NN * ICH;

  const int swz  = (l31 & 7) << 4;
  const int koff = 16 * ((lane & 7) ^ (lane >> 3));

  // theta B-fragments (held whole kernel): col q = nw + l31, k-slice ks*16 + hi*8
  bf16x8 aq[4];
#pragma unroll
  for (int ks = 0; ks < 4; ++ks)
    aq[ks] = *(const bf16x8*)(thp + bbase + (size_t)(nw + l31) * ICH + ks * 16 + hi * 8);

  f32x16 yacc[2];
  yacc[0] = zero16(); yacc[1] = zero16();
  float Lp = 0.f;

  const char* ph_g = (const char*)php + bbase * 2;
  const char* gt_g = (const char*)gtp + (size_t)b * ICH * NN * 2;
  const int m_start = s * KSPLIT;

  auto stage = [&](int mt, int buf) {
    const int m0 = m_start + mt * 64;
#pragma unroll
    for (int u = 0; u < 2; ++u) {
      const int kk = wave * 2 + u;
      const int row = kk * 8 + (lane >> 3);
      gl_lds16(ph_g + (size_t)(m0 + row) * 128 + koff, (char*)ph_s[buf] + kk * 1024);
      gl_lds16(gt_g + (size_t)row * (NN * 2) + m0 * 2 + koff, (char*)gt_s[buf] + kk * 1024);
    }
  };

  stage(0, 0);
  for (int mt = 0; mt < MT; ++mt) {
    __syncthreads();                     // staged tile mt visible (vmcnt drained)
    if (mt + 1 < MT) stage(mt + 1, (mt + 1) & 1);
    const char* phb = (const char*)ph_s[mt & 1];
    const char* gtb = (const char*)gt_s[mt & 1];

#pragma unroll
    for (int c = 0; c < 2; ++c) {        // key chunks of 32
      // S^T = phi . theta^T : A-frag = phi rows (keys)
      bf16x8 pf4[4];
#pragma unroll
      for (int ks = 0; ks < 4; ++ks)
        pf4[ks] = *(const bf16x8*)(phb + (c * 32 + l31) * 128 +
                                   ((ks * 32 + hi * 16) ^ swz));
      f32x16 sacc = zero16();
#pragma unroll
      for (int ks = 0; ks < 4; ++ks)
        sacc = mfma32(pf4[ks], aq[ks], sacc);

      // softmax + in-register P fragments (cvt_pk + permlane32_swap)
      float p[16];
#pragma unroll
      for (int r = 0; r < 16; ++r) {
        p[r] = __expf(sacc[r] - 8.0f);
        Lp += p[r];
      }
      unsigned pk[8];
#pragma unroll
      for (int km = 0; km < 2; ++km) {
        unsigned P0 = cvtpk(p[km * 8 + 0], p[km * 8 + 1]);
        unsigned P1 = cvtpk(p[km * 8 + 2], p[km * 8 + 3]);
        unsigned P2 = cvtpk(p[km * 8 + 4], p[km * 8 + 5]);
        unsigned P3 = cvtpk(p[km * 8 + 6], p[km * 8 + 7]);
        pl32swap(P0, P2);
        pl32swap(P1, P3);
        pk[km * 4 + 0] = P0; pk[km * 4 + 1] = P1;
        pk[km * 4 + 2] = P2; pk[km * 4 + 3] = P3;
      }
      bf16x8 pB0 = frag4(pk[0], pk[1], pk[2], pk[3]);
      bf16x8 pB1 = frag4(pk[4], pk[5], pk[6], pk[7]);

      // PV: y^T = g^T . P^T
#pragma unroll
      for (int ci = 0; ci < 2; ++ci) {
        bf16x8 gA0 = *(const bf16x8*)(gtb + (ci * 32 + l31) * 128 +
                                      ((c * 64 + 0  + hi * 16) ^ swz));
        bf16x8 gA1 = *(const bf16x8*)(gtb + (ci * 32 + l31) * 128 +
                                      ((c * 64 + 32 + hi * 16) ^ swz));
        yacc[ci] = mfma32(gA0, pB0, yacc[ci]);
        yacc[ci] = mfma32(gA1, pB1, yacc[ci]);
      }
    }
  }

  // L: own 16-key partials + partner half
  Lp += __shfl_xor(Lp, 32);

  const size_t pbase = ((size_t)s * BB + b) * NN;
  if (hi == 0) Lq[pbase + nw + l31] = Lp;

  const size_t qg = pbase + nw + l31;
#pragma unroll
  for (int ci = 0; ci < 2; ++ci)
#pragma unroll
    for (int rg = 0; rg < 4; ++rg) {
      u16 o4[4];
#pragma unroll
      for (int j = 0; j < 4; ++j) o4[j] = f2bf(yacc[ci][rg * 4 + j]);
      *(unsigned long long*)(yp + qg * ICH + ci * 32 + 8 * rg + 4 * hi) =
          *(unsigned long long*)o4;
    }
}

// ---------------- Kernel 3: combine partials, out = W.y + Wb + x (R6 verbatim) ------
// grid: BB * (NN/32) = 512 blocks, 256 threads
__global__ __launch_bounds__(256) void out_kernel(
    const float* __restrict__ x, const float* __restrict__ Ww,
    const float* __restrict__ Wb, const u16* __restrict__ yp,
    const float* __restrict__ Lq, float* __restrict__ out)
{
  __shared__ __align__(16) u16 ys[4096];   // [32 n][64 ic] bf16, 128B rows, swz
  const int t = threadIdx.x, lane = t & 63;
  const int wave = t >> 6, l31 = lane & 31, hi = lane >> 5;
  const int b  = blockIdx.x >> 7;
  const int n0 = (blockIdx.x & 127) << 5;

  // phase 0: combine the SS partials -> normalized y (bf16) in LDS
  {
    const int n = t >> 3, i8 = t & 7;
    float den = 0.f;
#pragma unroll
    for (int s = 0; s < SS; ++s) den += Lq[((size_t)s * BB + b) * NN + n0 + n];
    float num[8];
#pragma unroll
    for (int j = 0; j < 8; ++j) num[j] = 0.f;
#pragma unroll
    for (int s = 0; s < SS; ++s) {
      bf16x8 v = *(const bf16x8*)(yp + (((size_t)s * BB + b) * NN + n0 + n) * ICH + i8 * 8);
#pragma unroll
      for (int j = 0; j < 8; ++j) num[j] += bf2f((u16)v[j]);
    }
    float rd = 1.f / den;
    u16 o[8];
#pragma unroll
    for (int j = 0; j < 8; ++j) o[j] = f2bf(num[j] * rd);
    *(bf16x8*)((char*)ys + n * 128 + ((i8 * 16) ^ ((n & 7) << 4))) = *(bf16x8*)o;
  }
  __syncthreads();

  // phase 1: W.y via MFMA; wave handles c-chunk wave*32
  f32x16 acc = zero16();
  const int crow = wave * 32 + l31;
#pragma unroll
  for (int ks = 0; ks < 4; ++ks) {
    const float* wp = Ww + crow * ICH + ks * 16 + hi * 8;
    float4 w0 = *(const float4*)wp, w1 = *(const float4*)(wp + 4);
    u16 af[8];
    af[0] = f2bf(w0.x); af[1] = f2bf(w0.y); af[2] = f2bf(w0.z); af[3] = f2bf(w0.w);
    af[4] = f2bf(w1.x); af[5] = f2bf(w1.y); af[6] = f2bf(w1.z); af[7] = f2bf(w1.w);
    bf16x8 bf = *(const bf16x8*)((char*)ys + l31 * 128 +
                                 ((ks * 32 + hi * 16) ^ ((l31 & 7) << 4)));
    acc = mfma32(*(const bf16x8*)af, bf, acc);
  }
#pragma unroll
  for (int reg = 0; reg < 16; ++reg) {
    const int c = wave * 32 + (reg & 3) + 8 * (reg >> 2) + 4 * hi;
    size_t o = ((size_t)(b * CC + c) << 12) + n0 + l31;
    out[o] = acc[reg] + Wb[c] + x[o];
  }
}

extern "C" void kernel_launch(void* const* d_in, const int* in_sizes, int n_in,
                              void* d_out, int out_size, void* d_ws, size_t ws_size,
                              hipStream_t stream) {
  const float* x  = (const float*)d_in[0];
  const float* gw = (const float*)d_in[1];
  const float* gb = (const float*)d_in[2];
  const float* tw = (const float*)d_in[3];
  const float* tb = (const float*)d_in[4];
  const float* pw = (const float*)d_in[5];
  const float* pb = (const float*)d_in[6];
  const float* Ww = (const float*)d_in[7];
  const float* Wb = (const float*)d_in[8];
  float* out = (float*)d_out;

  char* ws = (char*)d_ws;
  u16*   th = (u16*)(ws);                      // 2MB
  u16*   ph = (u16*)(ws + (2ull << 20));       // 2MB
  u16*   gt = (u16*)(ws + (4ull << 20));       // 2MB
  u16*   yp = (u16*)(ws + (6ull << 20));       // SS*B*N*IC bf16 = 16MB
  float* Lq = (float*)(ws + (22ull << 20));    // SS*B*N f32 = 512KB

  proj_kernel<<<512, 384, 0, stream>>>(x, gw, gb, tw, tb, pw, pb, th, ph, gt);
  attn_kernel<<<BB * (NN / 128) * SS, 256, 0, stream>>>(th, ph, gt, yp, Lq);
  out_kernel<<<512, 256, 0, stream>>>(x, Ww, Wb, yp, Lq, out);
}

// Round 8
// 51.757 us; speedup vs baseline: 1.6921x; 1.1161x over previous
//
#include <hip/hip_runtime.h>
#include <hip/hip_bf16.h>

#define BB  4
#define CC  128
#define ICH 64
#define NN  4096
#define SS  8            // KV split factor
#define KSPLIT (NN / SS) // 512 keys per block
#define MT (KSPLIT / 64) // 8 key-tiles per block

typedef __attribute__((ext_vector_type(4)))  float f32x4;
typedef __attribute__((ext_vector_type(16))) float f32x16;
typedef __attribute__((ext_vector_type(8)))  short bf16x8;
typedef __attribute__((ext_vector_type(4)))  unsigned u32x4;
typedef unsigned short u16;

static __device__ __forceinline__ f32x16 mfma32(bf16x8 a, bf16x8 b, f32x16 c) {
  return __builtin_amdgcn_mfma_f32_32x32x16_bf16(a, b, c, 0, 0, 0);
}
static __device__ __forceinline__ u16 f2bf(float f) {
  __hip_bfloat16 h = __float2bfloat16(f);
  return *reinterpret_cast<u16*>(&h);
}
static __device__ __forceinline__ float bf2f(u16 u) {
  union { unsigned int i; float f; } v; v.i = ((unsigned int)u) << 16; return v.f;
}
static __device__ __forceinline__ void gl_lds16(const void* g, void* l) {
  __builtin_amdgcn_global_load_lds((const __attribute__((address_space(1))) void*)g,
                                   (__attribute__((address_space(3))) void*)l, 16, 0, 0);
}
static __device__ __forceinline__ f32x16 zero16() {
  f32x16 v;
#pragma unroll
  for (int i = 0; i < 16; ++i) v[i] = 0.f;
  return v;
}
static __device__ __forceinline__ unsigned cvtpk(float lo, float hi_) {
  unsigned r;
  asm("v_cvt_pk_bf16_f32 %0, %1, %2" : "=v"(r) : "v"(lo), "v"(hi_));
  return r;
}
static __device__ __forceinline__ void pl32swap(unsigned &a, unsigned &b) {
  asm("v_permlane32_swap_b32 %0, %1" : "+v"(a), "+v"(b));
}
static __device__ __forceinline__ bf16x8 frag4(unsigned w0, unsigned w1,
                                               unsigned w2, unsigned w3) {
  union { u32x4 w; bf16x8 h; } u;
  u.w[0] = w0; u.w[1] = w1; u.w[2] = w2; u.w[3] = w3;
  return u.h;
}

// ---------------- Kernel 1: projections via MFMA (R7 verbatim — validated) ----------
// grid: BB * (NN/32) = 512 blocks, 384 threads (6 waves).
__global__ __launch_bounds__(384) void proj_kernel(
    const float* __restrict__ x,
    const float* __restrict__ gw, const float* __restrict__ gb,
    const float* __restrict__ tw, const float* __restrict__ tb,
    const float* __restrict__ pw, const float* __restrict__ pb,
    u16* __restrict__ th, u16* __restrict__ ph, u16* __restrict__ gt)
{
  __shared__ __align__(16) float xs[CC * 32];   // [c][32 n], 128B rows
  const int t = threadIdx.x, wave = t / 64, lane = t & 63;
  const int l31 = lane & 31, hi = lane >> 5;
  const int b  = blockIdx.x >> 7;
  const int n0 = (blockIdx.x & 127) << 5;

  // stage x tile [128 c][32 n] f32 (16KB) via plain vector loads
  for (int idx = t; idx < CC * 8; idx += 384) {   // 1024 float4 chunks
    const int c = idx >> 3, n4 = idx & 7;
    *(float4*)&xs[c * 32 + n4 * 4] =
        *(const float4*)(x + ((size_t)(b * CC + c) << 12) + n0 + n4 * 4);
  }

  const int pt  = wave >> 1;
  const int ic0 = (wave & 1) << 5;
  const float* wsel = (pt == 0) ? gw : (pt == 1) ? tw : pw;

  // weight fragments: A-row / B-col = ic0 + l31, k-slot (hi,j) <-> c = ks*16 + hi*8 + j
  bf16x8 wfrag[8];
  {
    const float* wrow = wsel + (ic0 + l31) * CC;
#pragma unroll
    for (int ks = 0; ks < 8; ++ks) {
      float4 a = *(const float4*)(wrow + ks * 16 + hi * 8);
      float4 c = *(const float4*)(wrow + ks * 16 + hi * 8 + 4);
      wfrag[ks] = frag4(cvtpk(a.x, a.y), cvtpk(a.z, a.w),
                        cvtpk(c.x, c.y), cvtpk(c.z, c.w));
    }
  }
  __syncthreads();

  // x fragments from LDS (bank = n -> conflict-free broadcast reads) + MFMA
  f32x16 acc = zero16();
  if (pt == 0) {
#pragma unroll
    for (int ks = 0; ks < 8; ++ks) {
      const float* xp = xs + (ks * 16 + hi * 8) * 32 + l31;
      bf16x8 xf = frag4(cvtpk(xp[0], xp[32]),   cvtpk(xp[64], xp[96]),
                        cvtpk(xp[128], xp[160]), cvtpk(xp[192], xp[224]));
      acc = mfma32(wfrag[ks], xf, acc);
    }
    // D[ic][n]: col = n0+l31, row (reg-mapped) = ic
#pragma unroll
    for (int reg = 0; reg < 16; ++reg) {
      const int ic = ic0 + (reg & 3) + 8 * (reg >> 2) + 4 * hi;
      gt[((size_t)(b * ICH + ic)) * NN + n0 + l31] = f2bf(acc[reg] + gb[ic]);
    }
  } else {
#pragma unroll
    for (int ks = 0; ks < 8; ++ks) {
      const float* xp = xs + (ks * 16 + hi * 8) * 32 + l31;
      bf16x8 xf = frag4(cvtpk(xp[0], xp[32]),   cvtpk(xp[64], xp[96]),
                        cvtpk(xp[128], xp[160]), cvtpk(xp[192], xp[224]));
      acc = mfma32(xf, wfrag[ks], acc);
    }
    u16* dst = (pt == 1) ? th : ph;
    const float bias = (pt == 1) ? tb[ic0 + l31] : pb[ic0 + l31];
    // D[n][ic]: col = ic0+l31, row (reg-mapped) = n
#pragma unroll
    for (int reg = 0; reg < 16; ++reg) {
      const int n = n0 + (reg & 3) + 8 * (reg >> 2) + 4 * hi;
      dst[((size_t)(b * NN + n)) * ICH + ic0 + l31] = f2bf(acc[reg] + bias);
    }
  }
}

// ---------------- Kernel 2: flash attention (R6 base + setprio + g-hoist) -----------
// grid: BB * (NN/128) * SS = 1024 blocks, 256 threads (4 waves x 32 query rows)
__global__ __launch_bounds__(256, 4) void attn_kernel(
    const u16* __restrict__ thp, const u16* __restrict__ php,
    const u16* __restrict__ gtp, u16* __restrict__ yp, float* __restrict__ Lq)
{
  __shared__ __align__(16) u16 ph_s[2][4096];  // [buf][64 keys][64 ic], 128B rows, swz
  __shared__ __align__(16) u16 gt_s[2][4096];  // [buf][64 ic][64 keys], 128B rows, swz

  const int t    = threadIdx.x;
  const int wave = t >> 6, lane = t & 63;
  const int l31  = lane & 31, hi = lane >> 5;
  const int bid  = blockIdx.x;
  const int s    = bid & 7;
  const int rb   = (bid >> 3) & 31;
  const int b    = bid >> 8;
  const int nw   = rb * 128 + wave * 32;      // wave's first query row
  const size_t bbase = (size_t)b * NN * ICH;

  const int swz  = (l31 & 7) << 4;
  const int koff = 16 * ((lane & 7) ^ (lane >> 3));

  // theta B-fragments (held whole kernel): col q = nw + l31, k-slice ks*16 + hi*8
  bf16x8 aq[4];
#pragma unroll
  for (int ks = 0; ks < 4; ++ks)
    aq[ks] = *(const bf16x8*)(thp + bbase + (size_t)(nw + l31) * ICH + ks * 16 + hi * 8);

  f32x16 yacc[2];
  yacc[0] = zero16(); yacc[1] = zero16();
  float Lpa = 0.f, Lpb = 0.f;

  const char* ph_g = (const char*)php + bbase * 2;
  const char* gt_g = (const char*)gtp + (size_t)b * ICH * NN * 2;
  const int m_start = s * KSPLIT;

  auto stage = [&](int mt, int buf) {
    const int m0 = m_start + mt * 64;
#pragma unroll
    for (int u = 0; u < 2; ++u) {
      const int kk = wave * 2 + u;
      const int row = kk * 8 + (lane >> 3);
      gl_lds16(ph_g + (size_t)(m0 + row) * 128 + koff, (char*)ph_s[buf] + kk * 1024);
      gl_lds16(gt_g + (size_t)row * (NN * 2) + m0 * 2 + koff, (char*)gt_s[buf] + kk * 1024);
    }
  };

  stage(0, 0);
  for (int mt = 0; mt < MT; ++mt) {
    __syncthreads();                     // staged tile mt visible (vmcnt drained)
    if (mt + 1 < MT) stage(mt + 1, (mt + 1) & 1);
    const char* phb = (const char*)ph_s[mt & 1];
    const char* gtb = (const char*)gt_s[mt & 1];

#pragma unroll
    for (int c = 0; c < 2; ++c) {        // key chunks of 32
      // S^T = phi . theta^T : A-frag = phi rows (keys)
      bf16x8 pf4[4];
#pragma unroll
      for (int ks = 0; ks < 4; ++ks)
        pf4[ks] = *(const bf16x8*)(phb + (c * 32 + l31) * 128 +
                                   ((ks * 32 + hi * 16) ^ swz));
      f32x16 sacc = zero16();
      __builtin_amdgcn_s_setprio(1);
#pragma unroll
      for (int ks = 0; ks < 4; ++ks)
        sacc = mfma32(pf4[ks], aq[ks], sacc);
      __builtin_amdgcn_s_setprio(0);

      // hoist PV g-fragment reads: ds pipe idle during QK latency + softmax VALU
      bf16x8 gA0 = *(const bf16x8*)(gtb + (0 * 32 + l31) * 128 +
                                    ((c * 64 + 0  + hi * 16) ^ swz));
      bf16x8 gA1 = *(const bf16x8*)(gtb + (0 * 32 + l31) * 128 +
                                    ((c * 64 + 32 + hi * 16) ^ swz));
      bf16x8 gB0 = *(const bf16x8*)(gtb + (1 * 32 + l31) * 128 +
                                    ((c * 64 + 0  + hi * 16) ^ swz));
      bf16x8 gB1 = *(const bf16x8*)(gtb + (1 * 32 + l31) * 128 +
                                    ((c * 64 + 32 + hi * 16) ^ swz));

      // softmax + in-register P fragments (cvt_pk + permlane32_swap)
      float p[16];
#pragma unroll
      for (int r = 0; r < 16; ++r) {
        p[r] = __expf(sacc[r] - 8.0f);
        if (r & 1) Lpb += p[r]; else Lpa += p[r];
      }
      unsigned pk[8];
#pragma unroll
      for (int km = 0; km < 2; ++km) {
        unsigned P0 = cvtpk(p[km * 8 + 0], p[km * 8 + 1]);
        unsigned P1 = cvtpk(p[km * 8 + 2], p[km * 8 + 3]);
        unsigned P2 = cvtpk(p[km * 8 + 4], p[km * 8 + 5]);
        unsigned P3 = cvtpk(p[km * 8 + 6], p[km * 8 + 7]);
        pl32swap(P0, P2);
        pl32swap(P1, P3);
        pk[km * 4 + 0] = P0; pk[km * 4 + 1] = P1;
        pk[km * 4 + 2] = P2; pk[km * 4 + 3] = P3;
      }
      bf16x8 pB0 = frag4(pk[0], pk[1], pk[2], pk[3]);
      bf16x8 pB1 = frag4(pk[4], pk[5], pk[6], pk[7]);

      // PV: y^T = g^T . P^T
      __builtin_amdgcn_s_setprio(1);
      yacc[0] = mfma32(gA0, pB0, yacc[0]);
      yacc[0] = mfma32(gA1, pB1, yacc[0]);
      yacc[1] = mfma32(gB0, pB0, yacc[1]);
      yacc[1] = mfma32(gB1, pB1, yacc[1]);
      __builtin_amdgcn_s_setprio(0);
    }
  }

  // L: own 16-key partials + partner half
  float Lp = Lpa + Lpb;
  Lp += __shfl_xor(Lp, 32);

  const size_t pbase = ((size_t)s * BB + b) * NN;
  if (hi == 0) Lq[pbase + nw + l31] = Lp;

  const size_t qg = pbase + nw + l31;
#pragma unroll
  for (int ci = 0; ci < 2; ++ci)
#pragma unroll
    for (int rg = 0; rg < 4; ++rg) {
      u16 o4[4];
#pragma unroll
      for (int j = 0; j < 4; ++j) o4[j] = f2bf(yacc[ci][rg * 4 + j]);
      *(unsigned long long*)(yp + qg * ICH + ci * 32 + 8 * rg + 4 * hi) =
          *(unsigned long long*)o4;
    }
}

// ---------------- Kernel 3: combine partials, out = W.y + Wb + x (8-wave) -----------
// grid: BB * (NN/32) = 512 blocks, 512 threads (8 waves; waves 0-3 do the MFMA)
__global__ __launch_bounds__(512) void out_kernel(
    const float* __restrict__ x, const float* __restrict__ Ww,
    const float* __restrict__ Wb, const u16* __restrict__ yp,
    const float* __restrict__ Lq, float* __restrict__ out)
{
  __shared__ float ysf[2][32][68];   // f32 half-sums, padded rows (conflict-light)
  __shared__ float dens[2][32];
  const int t = threadIdx.x, lane = t & 63;
  const int wave = t >> 6, l31 = lane & 31, hi = lane >> 5;
  const int b  = blockIdx.x >> 7;
  const int n0 = (blockIdx.x & 127) << 5;

  // phase 0: each thread combines 4 of the 8 partials for one (n, 8-ic chunk)
  {
    const int i8 = t & 7, sh = (t >> 3) & 1, n = t >> 4;
    float num[8];
#pragma unroll
    for (int j = 0; j < 8; ++j) num[j] = 0.f;
#pragma unroll
    for (int si = 0; si < 4; ++si) {
      const int s = sh * 4 + si;
      bf16x8 v = *(const bf16x8*)(yp + (((size_t)s * BB + b) * NN + n0 + n) * ICH + i8 * 8);
#pragma unroll
      for (int j = 0; j < 8; ++j) num[j] += bf2f((u16)v[j]);
    }
    *(float4*)&ysf[sh][n][i8 * 8]     = make_float4(num[0], num[1], num[2], num[3]);
    *(float4*)&ysf[sh][n][i8 * 8 + 4] = make_float4(num[4], num[5], num[6], num[7]);
    if (i8 == 0) {
      float den = 0.f;
#pragma unroll
      for (int si = 0; si < 4; ++si)
        den += Lq[((size_t)(sh * 4 + si) * BB + b) * NN + n0 + n];
      dens[sh][n] = den;
    }
  }
  __syncthreads();

  // phase 1: W.y via MFMA; waves 0-3, wave handles c-chunk wave*32
  if (wave < 4) {
    const float rd = 1.f / (dens[0][l31] + dens[1][l31]);
    f32x16 acc = zero16();
    const int crow = wave * 32 + l31;
#pragma unroll
    for (int ks = 0; ks < 4; ++ks) {
      const float* wp = Ww + crow * ICH + ks * 16 + hi * 8;
      float4 w0 = *(const float4*)wp, w1 = *(const float4*)(wp + 4);
      u16 af[8];
      af[0] = f2bf(w0.x); af[1] = f2bf(w0.y); af[2] = f2bf(w0.z); af[3] = f2bf(w0.w);
      af[4] = f2bf(w1.x); af[5] = f2bf(w1.y); af[6] = f2bf(w1.z); af[7] = f2bf(w1.w);
      const int base = ks * 16 + hi * 8;
      float4 a0 = *(const float4*)&ysf[0][l31][base];
      float4 a1 = *(const float4*)&ysf[0][l31][base + 4];
      float4 b0 = *(const float4*)&ysf[1][l31][base];
      float4 b1 = *(const float4*)&ysf[1][l31][base + 4];
      bf16x8 bf = frag4(cvtpk((a0.x + b0.x) * rd, (a0.y + b0.y) * rd),
                        cvtpk((a0.z + b0.z) * rd, (a0.w + b0.w) * rd),
                        cvtpk((a1.x + b1.x) * rd, (a1.y + b1.y) * rd),
                        cvtpk((a1.z + b1.z) * rd, (a1.w + b1.w) * rd));
      acc = mfma32(*(const bf16x8*)af, bf, acc);
    }
#pragma unroll
    for (int reg = 0; reg < 16; ++reg) {
      const int c = wave * 32 + (reg & 3) + 8 * (reg >> 2) + 4 * hi;
      size_t o = ((size_t)(b * CC + c) << 12) + n0 + l31;
      out[o] = acc[reg] + Wb[c] + x[o];
    }
  }
}

extern "C" void kernel_launch(void* const* d_in, const int* in_sizes, int n_in,
                              void* d_out, int out_size, void* d_ws, size_t ws_size,
                              hipStream_t stream) {
  const float* x  = (const float*)d_in[0];
  const float* gw = (const float*)d_in[1];
  const float* gb = (const float*)d_in[2];
  const float* tw = (const float*)d_in[3];
  const float* tb = (const float*)d_in[4];
  const float* pw = (const float*)d_in[5];
  const float* pb = (const float*)d_in[6];
  const float* Ww = (const float*)d_in[7];
  const float* Wb = (const float*)d_in[8];
  float* out = (float*)d_out;

  char* ws = (char*)d_ws;
  u16*   th = (u16*)(ws);                      // 2MB
  u16*   ph = (u16*)(ws + (2ull << 20));       // 2MB
  u16*   gt = (u16*)(ws + (4ull << 20));       // 2MB
  u16*   yp = (u16*)(ws + (6ull << 20));       // SS*B*N*IC bf16 = 16MB
  float* Lq = (float*)(ws + (22ull << 20));    // SS*B*N f32 = 512KB

  proj_kernel<<<512, 384, 0, stream>>>(x, gw, gb, tw, tb, pw, pb, th, ph, gt);
  attn_kernel<<<BB * (NN / 128) * SS, 256, 0, stream>>>(th, ph, gt, yp, Lq);
  out_kernel<<<512, 512, 0, stream>>>(x, Ww, Wb, yp, Lq, out);
}

// Round 9
// 51.743 us; speedup vs baseline: 1.6926x; 1.0003x over previous
//
#include <hip/hip_runtime.h>
#include <hip/hip_bf16.h>

#define BB  4
#define CC  128
#define ICH 64
#define NN  4096
#define SS  8            // KV split factor
#define KSPLIT (NN / SS) // 512 keys per block
#define MT (KSPLIT / 64) // 8 key-tiles per block

typedef __attribute__((ext_vector_type(4)))  float f32x4;
typedef __attribute__((ext_vector_type(16))) float f32x16;
typedef __attribute__((ext_vector_type(8)))  short bf16x8;
typedef __attribute__((ext_vector_type(4)))  unsigned u32x4;
typedef unsigned short u16;

static __device__ __forceinline__ f32x16 mfma32(bf16x8 a, bf16x8 b, f32x16 c) {
  return __builtin_amdgcn_mfma_f32_32x32x16_bf16(a, b, c, 0, 0, 0);
}
static __device__ __forceinline__ u16 f2bf(float f) {
  __hip_bfloat16 h = __float2bfloat16(f);
  return *reinterpret_cast<u16*>(&h);
}
static __device__ __forceinline__ float bf2f(u16 u) {
  union { unsigned int i; float f; } v; v.i = ((unsigned int)u) << 16; return v.f;
}
static __device__ __forceinline__ void gl_lds16(const void* g, void* l) {
  __builtin_amdgcn_global_load_lds((const __attribute__((address_space(1))) void*)g,
                                   (__attribute__((address_space(3))) void*)l, 16, 0, 0);
}
static __device__ __forceinline__ f32x16 zero16() {
  f32x16 v;
#pragma unroll
  for (int i = 0; i < 16; ++i) v[i] = 0.f;
  return v;
}
static __device__ __forceinline__ unsigned cvtpk(float lo, float hi_) {
  unsigned r;
  asm("v_cvt_pk_bf16_f32 %0, %1, %2" : "=v"(r) : "v"(lo), "v"(hi_));
  return r;
}
static __device__ __forceinline__ void pl32swap(unsigned &a, unsigned &b) {
  asm("v_permlane32_swap_b32 %0, %1" : "+v"(a), "+v"(b));
}
static __device__ __forceinline__ bf16x8 frag4(unsigned w0, unsigned w1,
                                               unsigned w2, unsigned w3) {
  union { u32x4 w; bf16x8 h; } u;
  u.w[0] = w0; u.w[1] = w1; u.w[2] = w2; u.w[3] = w3;
  return u.h;
}

// ---------------- Kernel 1: projections via MFMA (R7 verbatim — validated) ----------
// grid: BB * (NN/32) = 512 blocks, 384 threads (6 waves).
__global__ __launch_bounds__(384) void proj_kernel(
    const float* __restrict__ x,
    const float* __restrict__ gw, const float* __restrict__ gb,
    const float* __restrict__ tw, const float* __restrict__ tb,
    const float* __restrict__ pw, const float* __restrict__ pb,
    u16* __restrict__ th, u16* __restrict__ ph, u16* __restrict__ gt)
{
  __shared__ __align__(16) float xs[CC * 32];   // [c][32 n], 128B rows
  const int t = threadIdx.x, wave = t / 64, lane = t & 63;
  const int l31 = lane & 31, hi = lane >> 5;
  const int b  = blockIdx.x >> 7;
  const int n0 = (blockIdx.x & 127) << 5;

  // stage x tile [128 c][32 n] f32 (16KB) via plain vector loads
  for (int idx = t; idx < CC * 8; idx += 384) {   // 1024 float4 chunks
    const int c = idx >> 3, n4 = idx & 7;
    *(float4*)&xs[c * 32 + n4 * 4] =
        *(const float4*)(x + ((size_t)(b * CC + c) << 12) + n0 + n4 * 4);
  }

  const int pt  = wave >> 1;
  const int ic0 = (wave & 1) << 5;
  const float* wsel = (pt == 0) ? gw : (pt == 1) ? tw : pw;

  // weight fragments: A-row / B-col = ic0 + l31, k-slot (hi,j) <-> c = ks*16 + hi*8 + j
  bf16x8 wfrag[8];
  {
    const float* wrow = wsel + (ic0 + l31) * CC;
#pragma unroll
    for (int ks = 0; ks < 8; ++ks) {
      float4 a = *(const float4*)(wrow + ks * 16 + hi * 8);
      float4 c = *(const float4*)(wrow + ks * 16 + hi * 8 + 4);
      wfrag[ks] = frag4(cvtpk(a.x, a.y), cvtpk(a.z, a.w),
                        cvtpk(c.x, c.y), cvtpk(c.z, c.w));
    }
  }
  __syncthreads();

  // x fragments from LDS (bank = n -> conflict-free broadcast reads) + MFMA
  f32x16 acc = zero16();
  if (pt == 0) {
#pragma unroll
    for (int ks = 0; ks < 8; ++ks) {
      const float* xp = xs + (ks * 16 + hi * 8) * 32 + l31;
      bf16x8 xf = frag4(cvtpk(xp[0], xp[32]),   cvtpk(xp[64], xp[96]),
                        cvtpk(xp[128], xp[160]), cvtpk(xp[192], xp[224]));
      acc = mfma32(wfrag[ks], xf, acc);
    }
    // D[ic][n]: col = n0+l31, row (reg-mapped) = ic
#pragma unroll
    for (int reg = 0; reg < 16; ++reg) {
      const int ic = ic0 + (reg & 3) + 8 * (reg >> 2) + 4 * hi;
      gt[((size_t)(b * ICH + ic)) * NN + n0 + l31] = f2bf(acc[reg] + gb[ic]);
    }
  } else {
#pragma unroll
    for (int ks = 0; ks < 8; ++ks) {
      const float* xp = xs + (ks * 16 + hi * 8) * 32 + l31;
      bf16x8 xf = frag4(cvtpk(xp[0], xp[32]),   cvtpk(xp[64], xp[96]),
                        cvtpk(xp[128], xp[160]), cvtpk(xp[192], xp[224]));
      acc = mfma32(xf, wfrag[ks], acc);
    }
    u16* dst = (pt == 1) ? th : ph;
    const float bias = (pt == 1) ? tb[ic0 + l31] : pb[ic0 + l31];
    // D[n][ic]: col = ic0+l31, row (reg-mapped) = n
#pragma unroll
    for (int reg = 0; reg < 16; ++reg) {
      const int n = n0 + (reg & 3) + 8 * (reg >> 2) + 4 * hi;
      dst[((size_t)(b * NN + n)) * ICH + ic0 + l31] = f2bf(acc[reg] + bias);
    }
  }
}

// ---------------- Kernel 2: flash attention (R8 base, register diet) ----------------
// grid: BB * (NN/128) * SS = 1024 blocks, 256 threads (4 waves x 32 query rows)
__global__ __launch_bounds__(256, 4) void attn_kernel(
    const u16* __restrict__ thp, const u16* __restrict__ php,
    const u16* __restrict__ gtp, u16* __restrict__ yp, float* __restrict__ Lq)
{
  __shared__ __align__(16) u16 ph_s[2][4096];  // [buf][64 keys][64 ic], 128B rows, swz
  __shared__ __align__(16) u16 gt_s[2][4096];  // [buf][64 ic][64 keys], 128B rows, swz

  const int t    = threadIdx.x;
  const int wave = t >> 6, lane = t & 63;
  const int l31  = lane & 31, hi = lane >> 5;
  const int bid  = blockIdx.x;
  const int s    = bid & 7;
  const int rb   = (bid >> 3) & 31;
  const int b    = bid >> 8;
  const int nw   = rb * 128 + wave * 32;      // wave's first query row
  const size_t bbase = (size_t)b * NN * ICH;

  const int swz  = (l31 & 7) << 4;
  const int koff = 16 * ((lane & 7) ^ (lane >> 3));

  // theta B-fragments (held whole kernel): col q = nw + l31, k-slice ks*16 + hi*8
  bf16x8 aq[4];
#pragma unroll
  for (int ks = 0; ks < 4; ++ks)
    aq[ks] = *(const bf16x8*)(thp + bbase + (size_t)(nw + l31) * ICH + ks * 16 + hi * 8);

  f32x16 yacc[2];
  yacc[0] = zero16(); yacc[1] = zero16();
  float Lpa = 0.f, Lpb = 0.f;

  const char* ph_g = (const char*)php + bbase * 2;
  const char* gt_g = (const char*)gtp + (size_t)b * ICH * NN * 2;
  const int m_start = s * KSPLIT;

  auto stage = [&](int mt, int buf) {
    const int m0 = m_start + mt * 64;
#pragma unroll
    for (int u = 0; u < 2; ++u) {
      const int kk = wave * 2 + u;
      const int row = kk * 8 + (lane >> 3);
      gl_lds16(ph_g + (size_t)(m0 + row) * 128 + koff, (char*)ph_s[buf] + kk * 1024);
      gl_lds16(gt_g + (size_t)row * (NN * 2) + m0 * 2 + koff, (char*)gt_s[buf] + kk * 1024);
    }
  };

  stage(0, 0);
  for (int mt = 0; mt < MT; ++mt) {
    __syncthreads();                     // staged tile mt visible (vmcnt drained)
    if (mt + 1 < MT) stage(mt + 1, (mt + 1) & 1);
    const char* phb = (const char*)ph_s[mt & 1];
    const char* gtb = (const char*)gt_s[mt & 1];

#pragma unroll
    for (int c = 0; c < 2; ++c) {        // key chunks of 32
      // S^T = phi . theta^T : A-frag = phi rows (keys)
      bf16x8 pf4[4];
#pragma unroll
      for (int ks = 0; ks < 4; ++ks)
        pf4[ks] = *(const bf16x8*)(phb + (c * 32 + l31) * 128 +
                                   ((ks * 32 + hi * 16) ^ swz));
      f32x16 sacc = zero16();
      __builtin_amdgcn_s_setprio(1);
#pragma unroll
      for (int ks = 0; ks < 4; ++ks)
        sacc = mfma32(pf4[ks], aq[ks], sacc);
      __builtin_amdgcn_s_setprio(0);

      // hoist yacc[0]'s g-fragments only (register diet: gB pair read late)
      bf16x8 gA0 = *(const bf16x8*)(gtb + (0 * 32 + l31) * 128 +
                                    ((c * 64 + 0  + hi * 16) ^ swz));
      bf16x8 gA1 = *(const bf16x8*)(gtb + (0 * 32 + l31) * 128 +
                                    ((c * 64 + 32 + hi * 16) ^ swz));

      // softmax fused: exp -> Lp accumulate -> cvt_pk immediately (no p[16] array)
      unsigned pk[8];
#pragma unroll
      for (int km = 0; km < 2; ++km) {
        unsigned P[4];
#pragma unroll
        for (int j = 0; j < 4; ++j) {
          float e0 = __expf(sacc[km * 8 + 2 * j]     - 8.0f);
          float e1 = __expf(sacc[km * 8 + 2 * j + 1] - 8.0f);
          Lpa += e0; Lpb += e1;
          P[j] = cvtpk(e0, e1);
        }
        pl32swap(P[0], P[2]);
        pl32swap(P[1], P[3]);
        pk[km * 4 + 0] = P[0]; pk[km * 4 + 1] = P[1];
        pk[km * 4 + 2] = P[2]; pk[km * 4 + 3] = P[3];
      }
      bf16x8 pB0 = frag4(pk[0], pk[1], pk[2], pk[3]);
      bf16x8 pB1 = frag4(pk[4], pk[5], pk[6], pk[7]);

      // PV: y^T = g^T . P^T ; gB reads issued under yacc[0]'s MFMA latency
      __builtin_amdgcn_s_setprio(1);
      yacc[0] = mfma32(gA0, pB0, yacc[0]);
      yacc[0] = mfma32(gA1, pB1, yacc[0]);
      bf16x8 gB0 = *(const bf16x8*)(gtb + (1 * 32 + l31) * 128 +
                                    ((c * 64 + 0  + hi * 16) ^ swz));
      bf16x8 gB1 = *(const bf16x8*)(gtb + (1 * 32 + l31) * 128 +
                                    ((c * 64 + 32 + hi * 16) ^ swz));
      yacc[1] = mfma32(gB0, pB0, yacc[1]);
      yacc[1] = mfma32(gB1, pB1, yacc[1]);
      __builtin_amdgcn_s_setprio(0);
    }
  }

  // L: own 16-key partials + partner half
  float Lp = Lpa + Lpb;
  Lp += __shfl_xor(Lp, 32);

  const size_t pbase = ((size_t)s * BB + b) * NN;
  if (hi == 0) Lq[pbase + nw + l31] = Lp;

  const size_t qg = pbase + nw + l31;
#pragma unroll
  for (int ci = 0; ci < 2; ++ci)
#pragma unroll
    for (int rg = 0; rg < 4; ++rg) {
      u16 o4[4];
#pragma unroll
      for (int j = 0; j < 4; ++j) o4[j] = f2bf(yacc[ci][rg * 4 + j]);
      *(unsigned long long*)(yp + qg * ICH + ci * 32 + 8 * rg + 4 * hi) =
          *(unsigned long long*)o4;
    }
}

// ---------------- Kernel 3: combine partials, out = W.y + Wb + x (R8 verbatim) ------
// grid: BB * (NN/32) = 512 blocks, 512 threads (8 waves; waves 0-3 do the MFMA)
__global__ __launch_bounds__(512) void out_kernel(
    const float* __restrict__ x, const float* __restrict__ Ww,
    const float* __restrict__ Wb, const u16* __restrict__ yp,
    const float* __restrict__ Lq, float* __restrict__ out)
{
  __shared__ float ysf[2][32][68];   // f32 half-sums, padded rows (conflict-light)
  __shared__ float dens[2][32];
  const int t = threadIdx.x, lane = t & 63;
  const int wave = t >> 6, l31 = lane & 31, hi = lane >> 5;
  const int b  = blockIdx.x >> 7;
  const int n0 = (blockIdx.x & 127) << 5;

  // phase 0: each thread combines 4 of the 8 partials for one (n, 8-ic chunk)
  {
    const int i8 = t & 7, sh = (t >> 3) & 1, n = t >> 4;
    float num[8];
#pragma unroll
    for (int j = 0; j < 8; ++j) num[j] = 0.f;
#pragma unroll
    for (int si = 0; si < 4; ++si) {
      const int s = sh * 4 + si;
      bf16x8 v = *(const bf16x8*)(yp + (((size_t)s * BB + b) * NN + n0 + n) * ICH + i8 * 8);
#pragma unroll
      for (int j = 0; j < 8; ++j) num[j] += bf2f((u16)v[j]);
    }
    *(float4*)&ysf[sh][n][i8 * 8]     = make_float4(num[0], num[1], num[2], num[3]);
    *(float4*)&ysf[sh][n][i8 * 8 + 4] = make_float4(num[4], num[5], num[6], num[7]);
    if (i8 == 0) {
      float den = 0.f;
#pragma unroll
      for (int si = 0; si < 4; ++si)
        den += Lq[((size_t)(sh * 4 + si) * BB + b) * NN + n0 + n];
      dens[sh][n] = den;
    }
  }
  __syncthreads();

  // phase 1: W.y via MFMA; waves 0-3, wave handles c-chunk wave*32
  if (wave < 4) {
    const float rd = 1.f / (dens[0][l31] + dens[1][l31]);
    f32x16 acc = zero16();
    const int crow = wave * 32 + l31;
#pragma unroll
    for (int ks = 0; ks < 4; ++ks) {
      const float* wp = Ww + crow * ICH + ks * 16 + hi * 8;
      float4 w0 = *(const float4*)wp, w1 = *(const float4*)(wp + 4);
      u16 af[8];
      af[0] = f2bf(w0.x); af[1] = f2bf(w0.y); af[2] = f2bf(w0.z); af[3] = f2bf(w0.w);
      af[4] = f2bf(w1.x); af[5] = f2bf(w1.y); af[6] = f2bf(w1.z); af[7] = f2bf(w1.w);
      const int base = ks * 16 + hi * 8;
      float4 a0 = *(const float4*)&ysf[0][l31][base];
      float4 a1 = *(const float4*)&ysf[0][l31][base + 4];
      float4 b0 = *(const float4*)&ysf[1][l31][base];
      float4 b1 = *(const float4*)&ysf[1][l31][base + 4];
      bf16x8 bf = frag4(cvtpk((a0.x + b0.x) * rd, (a0.y + b0.y) * rd),
                        cvtpk((a0.z + b0.z) * rd, (a0.w + b0.w) * rd),
                        cvtpk((a1.x + b1.x) * rd, (a1.y + b1.y) * rd),
                        cvtpk((a1.z + b1.z) * rd, (a1.w + b1.w) * rd));
      acc = mfma32(*(const bf16x8*)af, bf, acc);
    }
#pragma unroll
    for (int reg = 0; reg < 16; ++reg) {
      const int c = wave * 32 + (reg & 3) + 8 * (reg >> 2) + 4 * hi;
      size_t o = ((size_t)(b * CC + c) << 12) + n0 + l31;
      out[o] = acc[reg] + Wb[c] + x[o];
    }
  }
}

extern "C" void kernel_launch(void* const* d_in, const int* in_sizes, int n_in,
                              void* d_out, int out_size, void* d_ws, size_t ws_size,
                              hipStream_t stream) {
  const float* x  = (const float*)d_in[0];
  const float* gw = (const float*)d_in[1];
  const float* gb = (const float*)d_in[2];
  const float* tw = (const float*)d_in[3];
  const float* tb = (const float*)d_in[4];
  const float* pw = (const float*)d_in[5];
  const float* pb = (const float*)d_in[6];
  const float* Ww = (const float*)d_in[7];
  const float* Wb = (const float*)d_in[8];
  float* out = (float*)d_out;

  char* ws = (char*)d_ws;
  u16*   th = (u16*)(ws);                      // 2MB
  u16*   ph = (u16*)(ws + (2ull << 20));       // 2MB
  u16*   gt = (u16*)(ws + (4ull << 20));       // 2MB
  u16*   yp = (u16*)(ws + (6ull << 20));       // SS*B*N*IC bf16 = 16MB
  float* Lq = (float*)(ws + (22ull << 20));    // SS*B*N f32 = 512KB

  proj_kernel<<<512, 384, 0, stream>>>(x, gw, gb, tw, tb, pw, pb, th, ph, gt);
  attn_kernel<<<BB * (NN / 128) * SS, 256, 0, stream>>>(th, ph, gt, yp, Lq);
  out_kernel<<<512, 512, 0, stream>>>(x, Ww, Wb, yp, Lq, out);
}